// Round 17
// baseline (248.072 us; speedup 1.0000x reference)
//
#include <hip/hip_runtime.h>
#include <hip/hip_fp16.h>

#define N_NODES 50000
#define N_EDGES 600000
#define HID 128
#define NCOPY 16
#define NPART 3125   // aggregate grid size; 16 nodes/block * 3125 = 50000 exactly

typedef __attribute__((ext_vector_type(8))) short bf16x8;
typedef __attribute__((ext_vector_type(8))) unsigned short u16x8;
typedef __attribute__((ext_vector_type(4))) float f32x4;
typedef __attribute__((ext_vector_type(2))) float f32x2;

__device__ __forceinline__ float bf2f(unsigned short u) {
    return __uint_as_float(((unsigned int)u) << 16);
}
__device__ __forceinline__ unsigned short f2bf(float f) {
    unsigned int u = __float_as_uint(f);
    u = (u + 0x7FFFu + ((u >> 16) & 1u)) >> 16;   // RNE
    return (unsigned short)u;
}

// hardware OCP e4m3 fp8 encode (single value -> byte)
__device__ __forceinline__ unsigned char fp8enc_hw(float f) {
    return (unsigned char)(__builtin_amdgcn_cvt_pk_fp8_f32(f, f, 0, false) & 0xff);
}

// ---------------- preprocessing ----------------

// init degcnt planes, cs, epk pad entries; also fused W^T hi/lo prep.
__global__ __launch_bounds__(256) void init_k(unsigned long long* degcnt, float* cs,
                                              unsigned* epk_pad,
                                              const float* __restrict__ W1,
                                              const float* __restrict__ Ws,
                                              unsigned short* __restrict__ Wt_hi,
                                              unsigned short* __restrict__ Wt_lo,
                                              int total) {
    int i = blockIdx.x * 256 + threadIdx.x;
    if (i < total) degcnt[i] = (i < N_NODES) ? (1ull << 32) : 0ull;  // self-loop in copy 0
    if (i < HID) cs[i] = 0.0f;
    if (i < 8) epk_pad[i] = 0u;   // src 0, weight fp16(0)
    if (i < 5 * 16384) {
        int l = i >> 14;
        int r = i & 16383;
        int n = r >> 7;
        int k = r & 127;
        const float* src = (l == 0) ? W1 : (Ws + (size_t)(l - 1) * 16384);
        float w = src[k * 128 + n];
        unsigned short hi = f2bf(w);
        unsigned short lo = f2bf(w - bf2f(hi));
        Wt_hi[i] = hi;
        Wt_lo[i] = lo;
    }
}

__global__ __launch_bounds__(256) void edge_deg_k(const int* __restrict__ edges,
                                                  const float* __restrict__ attr,
                                                  unsigned long long* degcnt,
                                                  int* __restrict__ rank) {
    int e = blockIdx.x * 256 + threadIdx.x;
    int copy = blockIdx.x & (NCOPY - 1);
    if (e < N_EDGES) {
        int c = edges[N_EDGES + e];             // target
        unsigned long long enc = (1ull << 43) +
            (unsigned long long)llrintf(attr[e] * 4294967296.0f);
        unsigned long long old = atomicAdd(&degcnt[(size_t)copy * N_NODES + c], enc);
        rank[e] = (int)(old >> 43);             // slot within (target, copy)
    }
}

// scan pass 1: sum NCOPY planes, per-copy bases, dinv; block-local exclusive scan of counts
__global__ __launch_bounds__(256) void scan1_k(const unsigned long long* __restrict__ degcnt,
                                               int* offs, int* bsum, float* dinv,
                                               int* __restrict__ cbase, int n) {
    __shared__ int s[256];
    int tid = threadIdx.x;
    int i = blockIdx.x * 256 + tid;
    int v = 0;
    if (i < n) {
        unsigned long long attrsum = 0;
        int running = 0;
        #pragma unroll
        for (int c = 0; c < NCOPY; ++c) {
            unsigned long long dc = degcnt[(size_t)c * n + i];
            cbase[i * NCOPY + c] = running;
            running += (int)(dc >> 43);
            attrsum += dc & ((1ull << 43) - 1);
        }
        v = running;
        float deg = (float)attrsum * (1.0f / 4294967296.0f);
        dinv[i] = rsqrtf(deg);
    }
    s[tid] = v; __syncthreads();
    for (int d = 1; d < 256; d <<= 1) {
        int t = (tid >= d) ? s[tid - d] : 0;
        __syncthreads();
        s[tid] += t;
        __syncthreads();
    }
    if (i < n) offs[i] = s[tid] - v;
    if (tid == 255) bsum[blockIdx.x] = s[255];
}

// scan3 with scan2 folded in: each block redundantly scans bsum[0..nb) in LDS
__global__ __launch_bounds__(256) void scan3_k(int* offs, const int* __restrict__ bsum,
                                               int* cbase, int n, int nb) {
    __shared__ int s[256];
    int tid = threadIdx.x;
    int bv = (tid < nb) ? bsum[tid] : 0;
    s[tid] = bv; __syncthreads();
    for (int d = 1; d < 256; d <<= 1) {
        int t = (tid >= d) ? s[tid - d] : 0;
        __syncthreads();
        s[tid] += t;
        __syncthreads();
    }
    int b = blockIdx.x;                       // grid == nb, so b < nb <= 256
    int pbase = s[b] - bsum[b];               // exclusive prefix for this block
    int i = b * 256 + tid;
    if (i < n) {
        int v = offs[i] + pbase;
        offs[i] = v;
        #pragma unroll
        for (int c = 0; c < NCOPY; ++c) cbase[i * NCOPY + c] += v;
    }
}

// no atomics: slot = cbase[target][copy] + rank[e]; epk packed (w_fp16:16 | src:16)
__global__ __launch_bounds__(256) void fill_k(const int* __restrict__ edges,
                                              const float* __restrict__ attr,
                                              const float* __restrict__ dinv,
                                              const int* __restrict__ cbase,
                                              const int* __restrict__ rank,
                                              unsigned* __restrict__ epk) {
    int e = blockIdx.x * 256 + threadIdx.x;
    int copy = blockIdx.x & (NCOPY - 1);
    if (e < N_EDGES) {
        int r = edges[e];                    // source
        int c = edges[N_EDGES + e];          // target
        float w = dinv[r] * attr[e] * dinv[c];
        __half hw = __float2half(w);
        unsigned pk = ((unsigned)__half_as_ushort(hw) << 16) | (unsigned)r;
        epk[cbase[c * NCOPY + copy] + rank[e]] = pk;
    }
}

// ---------------- MFMA GEMM: H[n x 128] = A[n x 128] @ (W_hi + W_lo), fp8 out ----------------

template <bool FP32A>
__global__ __launch_bounds__(256) void mfma_gemm_k(const void* __restrict__ Av,
                                                   const unsigned short* __restrict__ Bh,
                                                   const unsigned short* __restrict__ Bl,
                                                   unsigned char* __restrict__ H, int nrows) {
    int wid  = threadIdx.x >> 6;
    int lane = threadIdx.x & 63;
    int row0 = blockIdx.x * 256 + wid * 64;
    int rl = lane & 15;          // A row within tile / B col
    int kg = lane >> 4;          // k-group (8 elems each)

    bf16x8 af[4][4];             // [row-tile][k-tile]
    #pragma unroll
    for (int rt = 0; rt < 4; ++rt) {
        int row = row0 + rt * 16 + rl;
        int ar  = row < nrows ? row : nrows - 1;
        #pragma unroll
        for (int kt = 0; kt < 4; ++kt) {
            if (FP32A) {
                const float* Af = (const float*)Av;
                float4 v0 = *(const float4*)(Af + (size_t)ar * HID + kt * 32 + kg * 8);
                float4 v1 = *(const float4*)(Af + (size_t)ar * HID + kt * 32 + kg * 8 + 4);
                bf16x8 t;
                t[0] = (short)f2bf(v0.x); t[1] = (short)f2bf(v0.y);
                t[2] = (short)f2bf(v0.z); t[3] = (short)f2bf(v0.w);
                t[4] = (short)f2bf(v1.x); t[5] = (short)f2bf(v1.y);
                t[6] = (short)f2bf(v1.z); t[7] = (short)f2bf(v1.w);
                af[rt][kt] = t;
            } else {
                const unsigned short* Ab = (const unsigned short*)Av;
                af[rt][kt] = *(const bf16x8*)(Ab + (size_t)ar * HID + kt * 32 + kg * 8);
            }
        }
    }

    f32x4 acc[4][8];
    #pragma unroll
    for (int rt = 0; rt < 4; ++rt)
        #pragma unroll
        for (int nt = 0; nt < 8; ++nt) acc[rt][nt] = (f32x4){0.f, 0.f, 0.f, 0.f};

    #pragma unroll
    for (int nt = 0; nt < 8; ++nt) {
        #pragma unroll
        for (int kt = 0; kt < 4; ++kt) {
            size_t boff = (size_t)(nt * 16 + rl) * HID + kt * 32 + kg * 8;
            bf16x8 bh = *(const bf16x8*)(Bh + boff);
            bf16x8 bl = *(const bf16x8*)(Bl + boff);
            #pragma unroll
            for (int rt = 0; rt < 4; ++rt) {
                acc[rt][nt] = __builtin_amdgcn_mfma_f32_16x16x32_bf16(af[rt][kt], bh, acc[rt][nt], 0, 0, 0);
                acc[rt][nt] = __builtin_amdgcn_mfma_f32_16x16x32_bf16(af[rt][kt], bl, acc[rt][nt], 0, 0, 0);
            }
        }
    }

    // D: col = lane&15, row = (lane>>4)*4 + reg
    #pragma unroll
    for (int rt = 0; rt < 4; ++rt) {
        #pragma unroll
        for (int nt = 0; nt < 8; ++nt) {
            #pragma unroll
            for (int r = 0; r < 4; ++r) {
                int orow = row0 + rt * 16 + kg * 4 + r;
                if (orow < nrows)
                    H[(size_t)orow * HID + nt * 16 + rl] = fp8enc_hw(acc[rt][nt][r]);
            }
        }
    }
}

// ---------------- aggregation: one 16-lane group per node (4 nodes/wave), branchless batch-8 ----------------

__device__ __forceinline__ void dec_fma8_pk(uint2 q, float wt, f32x2* a) {
    f32x2 w2 = {wt, wt};
    a[0] += __builtin_amdgcn_cvt_pk_f32_fp8((int)q.x, false) * w2;
    a[1] += __builtin_amdgcn_cvt_pk_f32_fp8((int)q.x, true)  * w2;
    a[2] += __builtin_amdgcn_cvt_pk_f32_fp8((int)q.y, false) * w2;
    a[3] += __builtin_amdgcn_cvt_pk_f32_fp8((int)q.y, true)  * w2;
}

template <bool FINAL>
__global__ __launch_bounds__(256) void aggregate_k(const unsigned char* __restrict__ h,
                                                   const int* __restrict__ offs,
                                                   const unsigned* __restrict__ epk,
                                                   const float* __restrict__ dinv,
                                                   const float* __restrict__ bias,
                                                   const unsigned short* __restrict__ xprev,
                                                   unsigned short* __restrict__ xout,
                                                   float* __restrict__ part, int n) {
    int tid  = threadIdx.x;
    int wave = (blockIdx.x * 256 + tid) >> 6;
    int lane = tid & 63;
    int g  = lane >> 4;                      // node slot within wave
    int ci = (lane & 15) * 8;                // 8 fp8 columns per lane
    int w = wave * 4 + g;                    // this group's node
    int wc = w < n ? w : n - 1;              // clamped row for pad gathers

    f32x2 a[4];
    #pragma unroll
    for (int j = 0; j < 4; ++j) a[j] = (f32x2){0.f, 0.f};

    int e0 = 0, e1 = 0;
    if (w < n) {
        e0 = offs[w];
        e1 = (w + 1 < n) ? offs[w + 1] : N_EDGES;
    }

    // branchless batches of 8: unconditional epk loads (padded), selects instead of guards
    for (int e = e0; e < e1; e += 8) {
        unsigned pk[8];
        uint2 q[8];
        #pragma unroll
        for (int u = 0; u < 8; ++u) pk[u] = epk[e + u];          // padded -> always in bounds
        #pragma unroll
        for (int u = 0; u < 8; ++u) {
            int row = (e + u < e1) ? (int)(pk[u] & 0xFFFFu) : wc;
            q[u] = *(const uint2*)(h + (size_t)row * HID + ci);
        }
        #pragma unroll
        for (int u = 0; u < 8; ++u) {
            float wt = (e + u < e1)
                ? __half2float(__ushort_as_half((unsigned short)(pk[u] >> 16))) : 0.f;
            dec_fma8_pk(q[u], wt, a);
        }
    }

    float av[8];
    #pragma unroll
    for (int j = 0; j < 8; ++j) av[j] = 0.f;

    if (w < n) {
        float di = dinv[w];
        uint2 qw = *(const uint2*)(h + (size_t)w * HID + ci);
        dec_fma8_pk(qw, di * di, a);
        av[0] = a[0][0]; av[1] = a[0][1]; av[2] = a[1][0]; av[3] = a[1][1];
        av[4] = a[2][0]; av[5] = a[2][1]; av[6] = a[3][0]; av[7] = a[3][1];
        float4 b0 = *(const float4*)(bias + ci);
        float4 b1 = *(const float4*)(bias + ci + 4);
        av[0] += b0.x; av[1] += b0.y; av[2] += b0.z; av[3] += b0.w;
        av[4] += b1.x; av[5] += b1.y; av[6] += b1.z; av[7] += b1.w;
        if (xprev) {
            u16x8 xp = *(const u16x8*)(xprev + (size_t)w * HID + ci);
            #pragma unroll
            for (int j = 0; j < 8; ++j) av[j] += bf2f(xp[j]);
        }
        u16x8 o;
        #pragma unroll
        for (int j = 0; j < 8; ++j) {
            av[j] = fmaxf(av[j], 0.f);
            o[j] = f2bf(av[j]);
        }
        *(u16x8*)(xout + (size_t)w * HID + ci) = o;
    }

    if constexpr (FINAL) {
        // reduce the 4 node-groups of this wave (same cols, lanes 16 apart)
        #pragma unroll
        for (int j = 0; j < 8; ++j) av[j] += __shfl_xor(av[j], 16);
        #pragma unroll
        for (int j = 0; j < 8; ++j) av[j] += __shfl_xor(av[j], 32);
        __shared__ float sw[4][16][8];
        int wv = tid >> 6;
        if (lane < 16) {
            #pragma unroll
            for (int j = 0; j < 8; ++j) sw[wv][lane][j] = av[j];
        }
        __syncthreads();
        if (tid < 128) {
            int l16 = tid >> 3, j = tid & 7;
            part[(size_t)tid * NPART + blockIdx.x] =
                sw[0][l16][j] + sw[1][l16][j] + sw[2][l16][j] + sw[3][l16][j];
        }
    }
}

// ---------------- head: reduce per-block partials, then tiny GEMV ----------------

__global__ __launch_bounds__(256) void head_reduce_k(const float* __restrict__ part,
                                                     float* __restrict__ cs) {
    int col = blockIdx.x;                    // 0..127
    float s = 0.f;
    for (int i = threadIdx.x; i < NPART; i += 256)
        s += part[(size_t)col * NPART + i];
    #pragma unroll
    for (int d = 1; d < 64; d <<= 1) s += __shfl_xor(s, d);
    __shared__ float sw[4];
    int lane = threadIdx.x & 63, wv = threadIdx.x >> 6;
    if (lane == 0) sw[wv] = s;
    __syncthreads();
    if (threadIdx.x == 0) cs[col] = sw[0] + sw[1] + sw[2] + sw[3];
}

__global__ __launch_bounds__(128) void final_k(const float* __restrict__ cs,
                                               const float* __restrict__ Wfc,
                                               const float* __restrict__ bfc,
                                               float* __restrict__ out) {
    __shared__ float s0[128], s1[128];
    int k = threadIdx.x;
    float c = cs[k];
    s0[k] = c * Wfc[k * 2 + 0];
    s1[k] = c * Wfc[k * 2 + 1];
    __syncthreads();
    for (int d = 64; d > 0; d >>= 1) {
        if (k < d) { s0[k] += s0[k + d]; s1[k] += s1[k + d]; }
        __syncthreads();
    }
    if (k == 0) {
        out[0] = s0[0] / (float)N_NODES + bfc[0];
        out[1] = s1[0] / (float)N_NODES + bfc[1];
    }
}

// ---------------- host ----------------

extern "C" void kernel_launch(void* const* d_in, const int* in_sizes, int n_in,
                              void* d_out, int out_size, void* d_ws, size_t ws_size,
                              hipStream_t stream) {
    const float* node  = (const float*)d_in[0];
    const int*   edges = (const int*)d_in[1];     // [2, E] int32
    const float* attr  = (const float*)d_in[2];
    const float* W1    = (const float*)d_in[3];
    const float* b1    = (const float*)d_in[4];
    const float* Ws    = (const float*)d_in[5];   // [4,128,128]
    const float* bs    = (const float*)d_in[6];   // [4,128]
    const float* Wfc   = (const float*)d_in[7];   // [128,2]
    const float* bfc   = (const float*)d_in[8];
    float* out = (float*)d_out;

    char* ws = (char*)d_ws;
    const size_t BN = (size_t)N_NODES * HID * 2;  // 12.8 MB plane
    unsigned char*  h8     = (unsigned char*)(ws);                 // 6.4 MB fp8
    unsigned short* xa_bf  = (unsigned short*)(ws + BN);
    unsigned short* xb_bf  = (unsigned short*)(ws + 2 * BN);
    char* p = ws + 3 * BN;
    unsigned long long* degcnt = (unsigned long long*)p; p += (size_t)NCOPY * N_NODES * 8;
    float* dinv  = (float*)p;            p += N_NODES * 4;
    int*   offs  = (int*)p;              p += N_NODES * 4;
    int*   cbase = (int*)p;              p += (size_t)N_NODES * NCOPY * 4;
    int*   rank  = (int*)p;              p += (size_t)N_EDGES * 4;
    int*   bsum  = (int*)p;              p += 1024;
    unsigned* epk = (unsigned*)p;        p += (size_t)(N_EDGES + 8) * 4;   // packed u32 + pad
    float* cs    = (float*)p;            p += 512;
    float* part  = (float*)p;            p += (size_t)128 * NPART * 4;     // 1.6 MB
    unsigned short* wt_hi = (unsigned short*)p;  p += 5 * 16384 * 2;
    unsigned short* wt_lo = (unsigned short*)p;  p += 5 * 16384 * 2;

    const int NB_N   = (N_NODES + 255) / 256;              // 196
    const int NB_N16 = (NCOPY * N_NODES + 255) / 256;      // 3125
    const int NB_E   = (N_EDGES + 255) / 256;              // 2344

    hipLaunchKernelGGL(init_k,     dim3(NB_N16), dim3(256), 0, stream, degcnt, cs,
                       epk + N_EDGES, W1, Ws, wt_hi, wt_lo, NCOPY * N_NODES);
    hipLaunchKernelGGL(edge_deg_k, dim3(NB_E),   dim3(256), 0, stream, edges, attr, degcnt, rank);
    hipLaunchKernelGGL(scan1_k,    dim3(NB_N),   dim3(256), 0, stream, degcnt, offs, bsum, dinv,
                       cbase, N_NODES);
    hipLaunchKernelGGL(scan3_k,    dim3(NB_N),   dim3(256), 0, stream, offs, bsum, cbase, N_NODES, NB_N);
    hipLaunchKernelGGL(fill_k,     dim3(NB_E),   dim3(256), 0, stream, edges, attr, dinv, cbase, rank, epk);

    const int GB = (N_NODES + 255) / 256;     // 196 (256 rows/block)
    const int AB = NPART;                     // 3125 (16 nodes/block)

    // layer 1: GEMM reads fp32 node directly
    hipLaunchKernelGGL((mfma_gemm_k<true>), dim3(GB), dim3(256), 0, stream,
                       (const void*)node, wt_hi, wt_lo, h8, N_NODES);
    hipLaunchKernelGGL((aggregate_k<false>), dim3(AB), dim3(256), 0, stream, h8, offs, epk, dinv,
                       b1, (const unsigned short*)nullptr, xa_bf, part, N_NODES);

    // 4 residual steps; last one fuses the column-sum head (partials, no atomics)
    unsigned short* xc = xa_bf;
    unsigned short* xn = xb_bf;
    for (int i = 0; i < 4; ++i) {
        hipLaunchKernelGGL((mfma_gemm_k<false>), dim3(GB), dim3(256), 0, stream,
                           (const void*)xc, wt_hi + (size_t)(i + 1) * 16384,
                           wt_lo + (size_t)(i + 1) * 16384, h8, N_NODES);
        if (i < 3) {
            hipLaunchKernelGGL((aggregate_k<false>), dim3(AB), dim3(256), 0, stream, h8, offs, epk, dinv,
                               bs + (size_t)i * HID, xc, xn, part, N_NODES);
        } else {
            hipLaunchKernelGGL((aggregate_k<true>), dim3(AB), dim3(256), 0, stream, h8, offs, epk, dinv,
                               bs + (size_t)i * HID, xc, xn, part, N_NODES);
        }
        unsigned short* t = xc; xc = xn; xn = t;
    }

    hipLaunchKernelGGL(head_reduce_k, dim3(128), dim3(256), 0, stream, part, cs);
    hipLaunchKernelGGL(final_k,       dim3(1),   dim3(128), 0, stream, cs, Wfc, bfc, out);
}

// Round 18
// 243.245 us; speedup vs baseline: 1.0198x; 1.0198x over previous
//
#include <hip/hip_runtime.h>
#include <hip/hip_fp16.h>

#define N_NODES 50000
#define N_EDGES 600000
#define HID 128
#define NCOPY 8
#define NPART 3125   // aggregate grid size; 16 nodes/block * 3125 = 50000 exactly

typedef __attribute__((ext_vector_type(8))) short bf16x8;
typedef __attribute__((ext_vector_type(8))) unsigned short u16x8;
typedef __attribute__((ext_vector_type(4))) float f32x4;
typedef __attribute__((ext_vector_type(2))) float f32x2;

__device__ __forceinline__ float bf2f(unsigned short u) {
    return __uint_as_float(((unsigned int)u) << 16);
}
__device__ __forceinline__ unsigned short f2bf(float f) {
    unsigned int u = __float_as_uint(f);
    u = (u + 0x7FFFu + ((u >> 16) & 1u)) >> 16;   // RNE
    return (unsigned short)u;
}

// hardware OCP e4m3 fp8 encode (single value -> byte)
__device__ __forceinline__ unsigned char fp8enc_hw(float f) {
    return (unsigned char)(__builtin_amdgcn_cvt_pk_fp8_f32(f, f, 0, false) & 0xff);
}

// ---------------- preprocessing ----------------

// init degcnt planes, cs, epk pad entries; also fused W^T hi/lo prep.
__global__ __launch_bounds__(256) void init_k(unsigned long long* degcnt, float* cs,
                                              unsigned* epk_pad,
                                              const float* __restrict__ W1,
                                              const float* __restrict__ Ws,
                                              unsigned short* __restrict__ Wt_hi,
                                              unsigned short* __restrict__ Wt_lo,
                                              int total) {
    int i = blockIdx.x * 256 + threadIdx.x;
    if (i < total) degcnt[i] = (i < N_NODES) ? (1ull << 32) : 0ull;  // self-loop in copy 0
    if (i < HID) cs[i] = 0.0f;
    if (i < 8) epk_pad[i] = 0u;   // src 0, weight fp16(0)
    if (i < 5 * 16384) {
        int l = i >> 14;
        int r = i & 16383;
        int n = r >> 7;
        int k = r & 127;
        const float* src = (l == 0) ? W1 : (Ws + (size_t)(l - 1) * 16384);
        float w = src[k * 128 + n];
        unsigned short hi = f2bf(w);
        unsigned short lo = f2bf(w - bf2f(hi));
        Wt_hi[i] = hi;
        Wt_lo[i] = lo;
    }
}

__global__ __launch_bounds__(256) void edge_deg_k(const int* __restrict__ edges,
                                                  const float* __restrict__ attr,
                                                  unsigned long long* degcnt,
                                                  int* __restrict__ rank) {
    int e = blockIdx.x * 256 + threadIdx.x;
    int copy = blockIdx.x & (NCOPY - 1);
    if (e < N_EDGES) {
        int c = edges[N_EDGES + e];             // target
        unsigned long long enc = (1ull << 43) +
            (unsigned long long)llrintf(attr[e] * 4294967296.0f);
        unsigned long long old = atomicAdd(&degcnt[(size_t)copy * N_NODES + c], enc);
        rank[e] = (int)(old >> 43);             // slot within (target, copy)
    }
}

// scan pass 1: sum NCOPY planes, per-copy bases, dinv; block-local exclusive scan of counts
__global__ __launch_bounds__(256) void scan1_k(const unsigned long long* __restrict__ degcnt,
                                               int* offs, int* bsum, float* dinv,
                                               int* __restrict__ cbase, int n) {
    __shared__ int s[256];
    int tid = threadIdx.x;
    int i = blockIdx.x * 256 + tid;
    int v = 0;
    if (i < n) {
        unsigned long long attrsum = 0;
        int running = 0;
        #pragma unroll
        for (int c = 0; c < NCOPY; ++c) {
            unsigned long long dc = degcnt[(size_t)c * n + i];
            cbase[i * NCOPY + c] = running;
            running += (int)(dc >> 43);
            attrsum += dc & ((1ull << 43) - 1);
        }
        v = running;
        float deg = (float)attrsum * (1.0f / 4294967296.0f);
        dinv[i] = rsqrtf(deg);
    }
    s[tid] = v; __syncthreads();
    for (int d = 1; d < 256; d <<= 1) {
        int t = (tid >= d) ? s[tid - d] : 0;
        __syncthreads();
        s[tid] += t;
        __syncthreads();
    }
    if (i < n) offs[i] = s[tid] - v;
    if (tid == 255) bsum[blockIdx.x] = s[255];
}

// scan3 with scan2 folded in: each block redundantly scans bsum[0..nb) in LDS
__global__ __launch_bounds__(256) void scan3_k(int* offs, const int* __restrict__ bsum,
                                               int* cbase, int n, int nb) {
    __shared__ int s[256];
    int tid = threadIdx.x;
    int bv = (tid < nb) ? bsum[tid] : 0;
    s[tid] = bv; __syncthreads();
    for (int d = 1; d < 256; d <<= 1) {
        int t = (tid >= d) ? s[tid - d] : 0;
        __syncthreads();
        s[tid] += t;
        __syncthreads();
    }
    int b = blockIdx.x;                       // grid == nb, so b < nb <= 256
    int pbase = s[b] - bsum[b];               // exclusive prefix for this block
    int i = b * 256 + tid;
    if (i < n) {
        int v = offs[i] + pbase;
        offs[i] = v;
        #pragma unroll
        for (int c = 0; c < NCOPY; ++c) cbase[i * NCOPY + c] += v;
    }
}

// no atomics: slot = cbase[target][copy] + rank[e]; epk packed (w_fp16:16 | src:16)
__global__ __launch_bounds__(256) void fill_k(const int* __restrict__ edges,
                                              const float* __restrict__ attr,
                                              const float* __restrict__ dinv,
                                              const int* __restrict__ cbase,
                                              const int* __restrict__ rank,
                                              unsigned* __restrict__ epk) {
    int e = blockIdx.x * 256 + threadIdx.x;
    int copy = blockIdx.x & (NCOPY - 1);
    if (e < N_EDGES) {
        int r = edges[e];                    // source
        int c = edges[N_EDGES + e];          // target
        float w = dinv[r] * attr[e] * dinv[c];
        __half hw = __float2half(w);
        unsigned pk = ((unsigned)__half_as_ushort(hw) << 16) | (unsigned)r;
        epk[cbase[c * NCOPY + copy] + rank[e]] = pk;
    }
}

// ---------------- MFMA GEMM: H[n x 128] = A[n x 128] @ (W_hi + W_lo), fp8 out ----------------

template <bool FP32A>
__global__ __launch_bounds__(256) void mfma_gemm_k(const void* __restrict__ Av,
                                                   const unsigned short* __restrict__ Bh,
                                                   const unsigned short* __restrict__ Bl,
                                                   unsigned char* __restrict__ H, int nrows) {
    int wid  = threadIdx.x >> 6;
    int lane = threadIdx.x & 63;
    int row0 = blockIdx.x * 256 + wid * 64;
    int rl = lane & 15;          // A row within tile / B col
    int kg = lane >> 4;          // k-group (8 elems each)

    bf16x8 af[4][4];             // [row-tile][k-tile]
    #pragma unroll
    for (int rt = 0; rt < 4; ++rt) {
        int row = row0 + rt * 16 + rl;
        int ar  = row < nrows ? row : nrows - 1;
        #pragma unroll
        for (int kt = 0; kt < 4; ++kt) {
            if (FP32A) {
                const float* Af = (const float*)Av;
                float4 v0 = *(const float4*)(Af + (size_t)ar * HID + kt * 32 + kg * 8);
                float4 v1 = *(const float4*)(Af + (size_t)ar * HID + kt * 32 + kg * 8 + 4);
                bf16x8 t;
                t[0] = (short)f2bf(v0.x); t[1] = (short)f2bf(v0.y);
                t[2] = (short)f2bf(v0.z); t[3] = (short)f2bf(v0.w);
                t[4] = (short)f2bf(v1.x); t[5] = (short)f2bf(v1.y);
                t[6] = (short)f2bf(v1.z); t[7] = (short)f2bf(v1.w);
                af[rt][kt] = t;
            } else {
                const unsigned short* Ab = (const unsigned short*)Av;
                af[rt][kt] = *(const bf16x8*)(Ab + (size_t)ar * HID + kt * 32 + kg * 8);
            }
        }
    }

    f32x4 acc[4][8];
    #pragma unroll
    for (int rt = 0; rt < 4; ++rt)
        #pragma unroll
        for (int nt = 0; nt < 8; ++nt) acc[rt][nt] = (f32x4){0.f, 0.f, 0.f, 0.f};

    #pragma unroll
    for (int nt = 0; nt < 8; ++nt) {
        #pragma unroll
        for (int kt = 0; kt < 4; ++kt) {
            size_t boff = (size_t)(nt * 16 + rl) * HID + kt * 32 + kg * 8;
            bf16x8 bh = *(const bf16x8*)(Bh + boff);
            bf16x8 bl = *(const bf16x8*)(Bl + boff);
            #pragma unroll
            for (int rt = 0; rt < 4; ++rt) {
                acc[rt][nt] = __builtin_amdgcn_mfma_f32_16x16x32_bf16(af[rt][kt], bh, acc[rt][nt], 0, 0, 0);
                acc[rt][nt] = __builtin_amdgcn_mfma_f32_16x16x32_bf16(af[rt][kt], bl, acc[rt][nt], 0, 0, 0);
            }
        }
    }

    // D: col = lane&15, row = (lane>>4)*4 + reg
    #pragma unroll
    for (int rt = 0; rt < 4; ++rt) {
        #pragma unroll
        for (int nt = 0; nt < 8; ++nt) {
            #pragma unroll
            for (int r = 0; r < 4; ++r) {
                int orow = row0 + rt * 16 + kg * 4 + r;
                if (orow < nrows)
                    H[(size_t)orow * HID + nt * 16 + rl] = fp8enc_hw(acc[rt][nt][r]);
            }
        }
    }
}

// ---------------- aggregation: one 16-lane group per node (4 nodes/wave), branchless batch-8 ----------------

__device__ __forceinline__ void dec_fma8_pk(uint2 q, float wt, f32x2* a) {
    f32x2 w2 = {wt, wt};
    a[0] += __builtin_amdgcn_cvt_pk_f32_fp8((int)q.x, false) * w2;
    a[1] += __builtin_amdgcn_cvt_pk_f32_fp8((int)q.x, true)  * w2;
    a[2] += __builtin_amdgcn_cvt_pk_f32_fp8((int)q.y, false) * w2;
    a[3] += __builtin_amdgcn_cvt_pk_f32_fp8((int)q.y, true)  * w2;
}

template <bool FINAL>
__global__ __launch_bounds__(256) void aggregate_k(const unsigned char* __restrict__ h,
                                                   const int* __restrict__ offs,
                                                   const unsigned* __restrict__ epk,
                                                   const float* __restrict__ dinv,
                                                   const float* __restrict__ bias,
                                                   const unsigned short* __restrict__ xprev,
                                                   unsigned short* __restrict__ xout,
                                                   float* __restrict__ part, int n) {
    int tid  = threadIdx.x;
    int wave = (blockIdx.x * 256 + tid) >> 6;
    int lane = tid & 63;
    int g  = lane >> 4;                      // node slot within wave
    int ci = (lane & 15) * 8;                // 8 fp8 columns per lane
    int w = wave * 4 + g;                    // this group's node
    int wc = w < n ? w : n - 1;              // clamped row for pad gathers

    f32x2 a[4];
    #pragma unroll
    for (int j = 0; j < 4; ++j) a[j] = (f32x2){0.f, 0.f};

    int e0 = 0, e1 = 0;
    if (w < n) {
        e0 = offs[w];
        e1 = (w + 1 < n) ? offs[w + 1] : N_EDGES;
    }

    // branchless batches of 8: unconditional epk loads (padded), selects instead of guards
    for (int e = e0; e < e1; e += 8) {
        unsigned pk[8];
        uint2 q[8];
        #pragma unroll
        for (int u = 0; u < 8; ++u) pk[u] = epk[e + u];          // padded -> always in bounds
        #pragma unroll
        for (int u = 0; u < 8; ++u) {
            int row = (e + u < e1) ? (int)(pk[u] & 0xFFFFu) : wc;
            q[u] = *(const uint2*)(h + (size_t)row * HID + ci);
        }
        #pragma unroll
        for (int u = 0; u < 8; ++u) {
            float wt = (e + u < e1)
                ? __half2float(__ushort_as_half((unsigned short)(pk[u] >> 16))) : 0.f;
            dec_fma8_pk(q[u], wt, a);
        }
    }

    float av[8];
    #pragma unroll
    for (int j = 0; j < 8; ++j) av[j] = 0.f;

    if (w < n) {
        float di = dinv[w];
        uint2 qw = *(const uint2*)(h + (size_t)w * HID + ci);
        dec_fma8_pk(qw, di * di, a);
        av[0] = a[0][0]; av[1] = a[0][1]; av[2] = a[1][0]; av[3] = a[1][1];
        av[4] = a[2][0]; av[5] = a[2][1]; av[6] = a[3][0]; av[7] = a[3][1];
        float4 b0 = *(const float4*)(bias + ci);
        float4 b1 = *(const float4*)(bias + ci + 4);
        av[0] += b0.x; av[1] += b0.y; av[2] += b0.z; av[3] += b0.w;
        av[4] += b1.x; av[5] += b1.y; av[6] += b1.z; av[7] += b1.w;
        if (xprev) {
            u16x8 xp = *(const u16x8*)(xprev + (size_t)w * HID + ci);
            #pragma unroll
            for (int j = 0; j < 8; ++j) av[j] += bf2f(xp[j]);
        }
        u16x8 o;
        #pragma unroll
        for (int j = 0; j < 8; ++j) {
            av[j] = fmaxf(av[j], 0.f);
            o[j] = f2bf(av[j]);
        }
        *(u16x8*)(xout + (size_t)w * HID + ci) = o;
    }

    if constexpr (FINAL) {
        // reduce the 4 node-groups of this wave (same cols, lanes 16 apart)
        #pragma unroll
        for (int j = 0; j < 8; ++j) av[j] += __shfl_xor(av[j], 16);
        #pragma unroll
        for (int j = 0; j < 8; ++j) av[j] += __shfl_xor(av[j], 32);
        __shared__ float sw[4][16][8];
        int wv = tid >> 6;
        if (lane < 16) {
            #pragma unroll
            for (int j = 0; j < 8; ++j) sw[wv][lane][j] = av[j];
        }
        __syncthreads();
        if (tid < 128) {
            int l16 = tid >> 3, j = tid & 7;
            part[(size_t)tid * NPART + blockIdx.x] =
                sw[0][l16][j] + sw[1][l16][j] + sw[2][l16][j] + sw[3][l16][j];
        }
    }
}

// ---------------- head: reduce per-block partials, then tiny GEMV ----------------

__global__ __launch_bounds__(256) void head_reduce_k(const float* __restrict__ part,
                                                     float* __restrict__ cs) {
    int col = blockIdx.x;                    // 0..127
    float s = 0.f;
    for (int i = threadIdx.x; i < NPART; i += 256)
        s += part[(size_t)col * NPART + i];
    #pragma unroll
    for (int d = 1; d < 64; d <<= 1) s += __shfl_xor(s, d);
    __shared__ float sw[4];
    int lane = threadIdx.x & 63, wv = threadIdx.x >> 6;
    if (lane == 0) sw[wv] = s;
    __syncthreads();
    if (threadIdx.x == 0) cs[col] = sw[0] + sw[1] + sw[2] + sw[3];
}

__global__ __launch_bounds__(128) void final_k(const float* __restrict__ cs,
                                               const float* __restrict__ Wfc,
                                               const float* __restrict__ bfc,
                                               float* __restrict__ out) {
    __shared__ float s0[128], s1[128];
    int k = threadIdx.x;
    float c = cs[k];
    s0[k] = c * Wfc[k * 2 + 0];
    s1[k] = c * Wfc[k * 2 + 1];
    __syncthreads();
    for (int d = 64; d > 0; d >>= 1) {
        if (k < d) { s0[k] += s0[k + d]; s1[k] += s1[k + d]; }
        __syncthreads();
    }
    if (k == 0) {
        out[0] = s0[0] / (float)N_NODES + bfc[0];
        out[1] = s1[0] / (float)N_NODES + bfc[1];
    }
}

// ---------------- host ----------------

extern "C" void kernel_launch(void* const* d_in, const int* in_sizes, int n_in,
                              void* d_out, int out_size, void* d_ws, size_t ws_size,
                              hipStream_t stream) {
    const float* node  = (const float*)d_in[0];
    const int*   edges = (const int*)d_in[1];     // [2, E] int32
    const float* attr  = (const float*)d_in[2];
    const float* W1    = (const float*)d_in[3];
    const float* b1    = (const float*)d_in[4];
    const float* Ws    = (const float*)d_in[5];   // [4,128,128]
    const float* bs    = (const float*)d_in[6];   // [4,128]
    const float* Wfc   = (const float*)d_in[7];   // [128,2]
    const float* bfc   = (const float*)d_in[8];
    float* out = (float*)d_out;

    char* ws = (char*)d_ws;
    const size_t BN = (size_t)N_NODES * HID * 2;  // 12.8 MB plane
    unsigned char*  h8     = (unsigned char*)(ws);                 // 6.4 MB fp8
    unsigned short* xa_bf  = (unsigned short*)(ws + BN);
    unsigned short* xb_bf  = (unsigned short*)(ws + 2 * BN);
    char* p = ws + 3 * BN;
    unsigned long long* degcnt = (unsigned long long*)p; p += (size_t)NCOPY * N_NODES * 8;
    float* dinv  = (float*)p;            p += N_NODES * 4;
    int*   offs  = (int*)p;              p += N_NODES * 4;
    int*   cbase = (int*)p;              p += (size_t)N_NODES * NCOPY * 4;
    int*   rank  = (int*)p;              p += (size_t)N_EDGES * 4;
    int*   bsum  = (int*)p;              p += 1024;
    unsigned* epk = (unsigned*)p;        p += (size_t)(N_EDGES + 8) * 4;   // packed u32 + pad
    float* cs    = (float*)p;            p += 512;
    float* part  = (float*)p;            p += (size_t)128 * NPART * 4;     // 1.6 MB
    unsigned short* wt_hi = (unsigned short*)p;  p += 5 * 16384 * 2;
    unsigned short* wt_lo = (unsigned short*)p;  p += 5 * 16384 * 2;

    const int NB_N  = (N_NODES + 255) / 256;             // 196
    const int NB_N8 = (NCOPY * N_NODES + 255) / 256;     // 1563
    const int NB_E  = (N_EDGES + 255) / 256;             // 2344

    hipLaunchKernelGGL(init_k,     dim3(NB_N8), dim3(256), 0, stream, degcnt, cs,
                       epk + N_EDGES, W1, Ws, wt_hi, wt_lo, NCOPY * N_NODES);
    hipLaunchKernelGGL(edge_deg_k, dim3(NB_E),  dim3(256), 0, stream, edges, attr, degcnt, rank);
    hipLaunchKernelGGL(scan1_k,    dim3(NB_N),  dim3(256), 0, stream, degcnt, offs, bsum, dinv,
                       cbase, N_NODES);
    hipLaunchKernelGGL(scan3_k,    dim3(NB_N),  dim3(256), 0, stream, offs, bsum, cbase, N_NODES, NB_N);
    hipLaunchKernelGGL(fill_k,     dim3(NB_E),  dim3(256), 0, stream, edges, attr, dinv, cbase, rank, epk);

    const int GB = (N_NODES + 255) / 256;     // 196 (256 rows/block)
    const int AB = NPART;                     // 3125 (16 nodes/block)

    // layer 1: GEMM reads fp32 node directly
    hipLaunchKernelGGL((mfma_gemm_k<true>), dim3(GB), dim3(256), 0, stream,
                       (const void*)node, wt_hi, wt_lo, h8, N_NODES);
    hipLaunchKernelGGL((aggregate_k<false>), dim3(AB), dim3(256), 0, stream, h8, offs, epk, dinv,
                       b1, (const unsigned short*)nullptr, xa_bf, part, N_NODES);

    // 4 residual steps; last one fuses the column-sum head (partials, no atomics)
    unsigned short* xc = xa_bf;
    unsigned short* xn = xb_bf;
    for (int i = 0; i < 4; ++i) {
        hipLaunchKernelGGL((mfma_gemm_k<false>), dim3(GB), dim3(256), 0, stream,
                           (const void*)xc, wt_hi + (size_t)(i + 1) * 16384,
                           wt_lo + (size_t)(i + 1) * 16384, h8, N_NODES);
        if (i < 3) {
            hipLaunchKernelGGL((aggregate_k<false>), dim3(AB), dim3(256), 0, stream, h8, offs, epk, dinv,
                               bs + (size_t)i * HID, xc, xn, part, N_NODES);
        } else {
            hipLaunchKernelGGL((aggregate_k<true>), dim3(AB), dim3(256), 0, stream, h8, offs, epk, dinv,
                               bs + (size_t)i * HID, xc, xn, part, N_NODES);
        }
        unsigned short* t = xc; xc = xn; xn = t;
    }

    hipLaunchKernelGGL(head_reduce_k, dim3(128), dim3(256), 0, stream, part, cs);
    hipLaunchKernelGGL(final_k,       dim3(1),   dim3(128), 0, stream, cs, Wfc, bfc, out);
}